// Round 8
// baseline (198.088 us; speedup 1.0000x reference)
//
#include <hip/hip_runtime.h>

#define Hh 32
#define Ss 2048
#define Ee 512
#define Dd 32
#define MNEG -1.0e9f
#define LOG2E 1.4426950408889634f
#define KV_SPLIT 4
#define KV_LEN (Ss / KV_SPLIT)   // 512 keys per wave

typedef __attribute__((ext_vector_type(4))) float f32x4;
typedef __attribute__((ext_vector_type(8))) __bf16 bf16x8;
typedef __attribute__((ext_vector_type(8))) unsigned short ushort8;
typedef __attribute__((ext_vector_type(4))) unsigned short ushort4v;

// float -> bf16 round-to-nearest-even, as raw ushort
__device__ inline unsigned short f2bf(float f) {
  union { float f; unsigned u; } x; x.f = f;
  unsigned r = x.u + 0x7fffu + ((x.u >> 16) & 1u);
  return (unsigned short)(r >> 16);
}

// ---------------- Prep: pack mask int32 -> bits, convert Wq|Wk|Wv -> bf16
__global__ __launch_bounds__(256) void prep_kernel(
    const int* __restrict__ mask, unsigned int* __restrict__ bits,
    const float* __restrict__ Wq, const float* __restrict__ Wk,
    const float* __restrict__ Wv, unsigned short* __restrict__ Wb) {
  int b = (int)blockIdx.x, t = (int)threadIdx.x;
  if (b < 512) {
    int w = b * 256 + t;  // word index 0..S*S/32-1
    const int4* p = (const int4*)(mask + (size_t)w * 32);
    unsigned int bs = 0;
    #pragma unroll
    for (int i = 0; i < 8; ++i) {
      int4 v = p[i];
      bs |= (v.x ? 1u : 0u) << (4 * i + 0);
      bs |= (v.y ? 1u : 0u) << (4 * i + 1);
      bs |= (v.z ? 1u : 0u) << (4 * i + 2);
      bs |= (v.w ? 1u : 0u) << (4 * i + 3);
    }
    bits[w] = bs;
  } else {
    int i = (b - 512) * 1024 + t * 4;  // 48 blocks cover 3*32*512 = 49152 elems
    const float* src = (i < 16384) ? (Wq + i)
                     : (i < 32768) ? (Wk + (i - 16384)) : (Wv + (i - 32768));
    float4 v = *(const float4*)src;
    ushort4v o = { f2bf(v.x), f2bf(v.y), f2bf(v.z), f2bf(v.w) };
    *(ushort4v*)(Wb + i) = o;
  }
}

// ---------------- Merged projections, BARRIER-FREE per-wave pipeline.
// Each wave owns 16 rows and a private 2x2KB LDS transpose scratch (LDS ops
// are in-order within a wave; compiler orders ds_write->ds_read via lgkmcnt;
// no cross-wave hazard -> zero barriers). Per chunk (64 cols): 4 coalesced
// dwordx4 loads (lane l -> row 4i+(l>>4), 16 consecutive bytes), fp32->bf16
// in regs, swizzled ds_write_b64 (byte ^ ((row&7)<<4)), then 2 conflict-free
// ds_read_b128 = MFMA A-frags. Depth-2 register prefetch with named A/B sets,
// fully unrolled (static indexing). Epilogues identical to passing kernel.
// seg 0=Q (prescaled by log2e/inv_scale), 1=K, 2=V (transposed+kk-permuted).
__global__ __launch_bounds__(256) void proj_kernel(
    const float* __restrict__ Xq, const float* __restrict__ Xk,
    const float* __restrict__ Xv, const unsigned short* __restrict__ Wb,
    const float* __restrict__ bq, const float* __restrict__ bk,
    const float* __restrict__ bv, const float* __restrict__ inv_scale,
    unsigned short* __restrict__ Qb, unsigned short* __restrict__ Kb,
    unsigned short* __restrict__ Vtb) {
  __shared__ unsigned short sb[4][2][16 * 64];   // [wave][buf][16 rows x 64 bf16]

  int blk  = (int)blockIdx.x;
  int seg  = blk >> 10;
  int tid  = (int)threadIdx.x;
  int wv   = tid >> 6, lane = tid & 63;
  int g = lane >> 4, li = lane & 15;
  int lr = lane >> 4;      // row-within-quad for loads (0..3)
  int lc = lane & 15;      // col group (4 floats = 16 B)
  int R0 = (blk & 1023) * 64;        // block row base within segment
  int h  = R0 >> 11;
  int s0 = R0 & 2047;

  const float* X    = (seg == 0) ? Xq : (seg == 1) ? Xk : Xv;
  const float* bias = (seg == 0) ? bq : (seg == 1) ? bk : bv;
  const unsigned short* W = Wb + seg * (Dd * Ee);
  const float* xw = X + (size_t)(R0 + wv * 16) * Ee;   // wave's 16 rows

  unsigned short (*mybuf)[16 * 64] = sb[wv];

  // chunk-c load i (i=0..3): row 4i+lr, cols c*64 + lc*4 .. +3
  auto ld = [&](int c, int i) -> float4 {
    return *(const float4*)(xw + (size_t)(4 * i + lr) * Ee + c * 64 + lc * 4);
  };
  auto wr = [&](int buf, int i, float4 v) {
    int r = 4 * i + lr;
    int byteoff = (lc * 8) ^ ((r & 7) << 4);
    ushort4v u = { f2bf(v.x), f2bf(v.y), f2bf(v.z), f2bf(v.w) };
    *(ushort4v*)&mybuf[buf][r * 64 + (byteoff >> 1)] = u;
  };
  auto rd = [&](int buf, int half) -> bf16x8 {
    int byteoff = (half * 64 + g * 16) ^ ((li & 7) << 4);
    return __builtin_bit_cast(bf16x8,
        *(const ushort8*)&mybuf[buf][li * 64 + (byteoff >> 1)]);
  };

  f32x4 acc0 = {0.f, 0.f, 0.f, 0.f};
  f32x4 acc1 = {0.f, 0.f, 0.f, 0.f};

  float4 A0 = ld(0, 0), A1 = ld(0, 1), A2 = ld(0, 2), A3 = ld(0, 3);
  float4 B0 = ld(1, 0), B1 = ld(1, 1), B2 = ld(1, 2), B3 = ld(1, 3);

  #pragma unroll
  for (int c = 0; c < 8; c += 2) {
    // even phase: consume A (chunk c) via buf0; refill A with chunk c+2
    wr(0, 0, A0); wr(0, 1, A1); wr(0, 2, A2); wr(0, 3, A3);
    {
      int cn = (c + 2 < 8) ? (c + 2) : 6;   // clamped redundant reload (L2-hot)
      A0 = ld(cn, 0); A1 = ld(cn, 1); A2 = ld(cn, 2); A3 = ld(cn, 3);
    }
    {
      const unsigned short* wl = W + (size_t)li * Ee + c * 64 + g * 8;
      ushort8 w00 = *(const ushort8*)(wl);
      ushort8 w01 = *(const ushort8*)(wl + 16 * Ee);
      ushort8 w10 = *(const ushort8*)(wl + 32);
      ushort8 w11 = *(const ushort8*)(wl + 16 * Ee + 32);
      bf16x8 a0 = rd(0, 0), a1 = rd(0, 1);
      acc0 = __builtin_amdgcn_mfma_f32_16x16x32_bf16(
          a0, __builtin_bit_cast(bf16x8, w00), acc0, 0, 0, 0);
      acc1 = __builtin_amdgcn_mfma_f32_16x16x32_bf16(
          a0, __builtin_bit_cast(bf16x8, w01), acc1, 0, 0, 0);
      acc0 = __builtin_amdgcn_mfma_f32_16x16x32_bf16(
          a1, __builtin_bit_cast(bf16x8, w10), acc0, 0, 0, 0);
      acc1 = __builtin_amdgcn_mfma_f32_16x16x32_bf16(
          a1, __builtin_bit_cast(bf16x8, w11), acc1, 0, 0, 0);
    }
    // odd phase: consume B (chunk c+1) via buf1; refill B with chunk c+3
    wr(1, 0, B0); wr(1, 1, B1); wr(1, 2, B2); wr(1, 3, B3);
    {
      int cn = (c + 3 < 8) ? (c + 3) : 7;
      B0 = ld(cn, 0); B1 = ld(cn, 1); B2 = ld(cn, 2); B3 = ld(cn, 3);
    }
    {
      const unsigned short* wl = W + (size_t)li * Ee + (c + 1) * 64 + g * 8;
      ushort8 w00 = *(const ushort8*)(wl);
      ushort8 w01 = *(const ushort8*)(wl + 16 * Ee);
      ushort8 w10 = *(const ushort8*)(wl + 32);
      ushort8 w11 = *(const ushort8*)(wl + 16 * Ee + 32);
      bf16x8 a0 = rd(1, 0), a1 = rd(1, 1);
      acc0 = __builtin_amdgcn_mfma_f32_16x16x32_bf16(
          a0, __builtin_bit_cast(bf16x8, w00), acc0, 0, 0, 0);
      acc1 = __builtin_amdgcn_mfma_f32_16x16x32_bf16(
          a0, __builtin_bit_cast(bf16x8, w01), acc1, 0, 0, 0);
      acc0 = __builtin_amdgcn_mfma_f32_16x16x32_bf16(
          a1, __builtin_bit_cast(bf16x8, w10), acc0, 0, 0, 0);
      acc1 = __builtin_amdgcn_mfma_f32_16x16x32_bf16(
          a1, __builtin_bit_cast(bf16x8, w11), acc1, 0, 0, 0);
    }
  }

  float blo = bias[li], bhi = bias[li + 16];
  float cs = (seg == 0) ? (LOG2E / inv_scale[h]) : 1.0f;
  int sw = s0 + wv * 16;                         // wave's 16-row base (in-head)
  if (seg < 2) {
    unsigned short* ob = ((seg == 0) ? Qb : Kb) +
        (size_t)h * Ss * Dd + (size_t)(sw + 4 * g) * Dd;
    #pragma unroll
    for (int r = 0; r < 4; ++r) {
      ob[r * Dd + li]      = f2bf((acc0[r] + blo) * cs);
      ob[r * Dd + li + 16] = f2bf((acc1[r] + bhi) * cs);
    }
  } else {
    unsigned short* ob = Vtb + (size_t)h * Dd * Ss;
    int s0v = sw + 4 * g;
    int base = (s0v & ~31) + 8 * g + ((s0v & 16) ? 4 : 0);  // PV kk-permuted
    #pragma unroll
    for (int r = 0; r < 4; ++r) {
      ob[(size_t)li * Ss + base + r]        = f2bf(acc0[r] + blo);
      ob[(size_t)(li + 16) * Ss + base + r] = f2bf(acc1[r] + bhi);
    }
  }
}

// ---------------- Flash attention: one BLOCK per (head, 16 q-rows); its 4
// waves each handle 512 keys (split-KV), combined at the end through LDS.
// Q pre-scaled by log2e/inv_scale -> exp2-domain softmax. Swapped QK: lane
// holds scores of ONE q-row (q=q0+li). Defer-max: common path has zero
// cross-lane ops. PV B-frag = single 16-B load from permuted Vt.
__global__ __launch_bounds__(256) void attn_kernel(
    const unsigned short* __restrict__ Qb, const unsigned short* __restrict__ Kb,
    const unsigned short* __restrict__ Vt, const unsigned int* __restrict__ mbits,
    float* __restrict__ out) {
  __shared__ float sO[KV_SPLIT][8][64];
  __shared__ float sM[KV_SPLIT][16];
  __shared__ float sL[KV_SPLIT][16];

  int bid  = (int)blockIdx.x;
  int slot = (bid & 7) * 512 + (bid >> 3);   // XCD-chunked, bijective (4096%8==0)
  int w    = (int)threadIdx.x >> 6;          // kv-split index 0..3
  int lane = (int)threadIdx.x & 63;
  int g = lane >> 4, li = lane & 15;
  int h = slot >> 7, qt = slot & 127;
  int q0 = qt << 4;

  const unsigned short* kb  = Kb + (size_t)h * Ss * Dd;
  const unsigned short* vpb = Vt + (size_t)h * Dd * Ss;
  bf16x8 qf = __builtin_bit_cast(bf16x8,
      *(const ushort8*)(Qb + (size_t)h * Ss * Dd + (size_t)(q0 + li) * Dd + g * 8));
  const unsigned int* mrow = mbits + (size_t)(q0 + li) * (Ss / 32);
  const unsigned short* vlo = vpb + (size_t)li * Ss + 8 * g;         // d = li
  const unsigned short* vhi = vpb + (size_t)(li + 16) * Ss + 8 * g;  // d = li+16

  f32x4 olo = {0.f, 0.f, 0.f, 0.f};
  f32x4 ohi = {0.f, 0.f, 0.f, 0.f};
  float M = -__builtin_inff(), Lp = 0.f;

  int kbeg = w * KV_LEN, kend = kbeg + KV_LEN;
  for (int kt = kbeg; kt < kend; kt += 64) {
    bf16x8 k0 = __builtin_bit_cast(bf16x8, *(const ushort8*)(kb + (size_t)(kt      + li) * Dd + g * 8));
    bf16x8 k1 = __builtin_bit_cast(bf16x8, *(const ushort8*)(kb + (size_t)(kt + 16 + li) * Dd + g * 8));
    bf16x8 k2 = __builtin_bit_cast(bf16x8, *(const ushort8*)(kb + (size_t)(kt + 32 + li) * Dd + g * 8));
    bf16x8 k3 = __builtin_bit_cast(bf16x8, *(const ushort8*)(kb + (size_t)(kt + 48 + li) * Dd + g * 8));
    bf16x8 v0lo = __builtin_bit_cast(bf16x8, *(const ushort8*)(vlo + kt));
    bf16x8 v0hi = __builtin_bit_cast(bf16x8, *(const ushort8*)(vhi + kt));
    bf16x8 v1lo = __builtin_bit_cast(bf16x8, *(const ushort8*)(vlo + kt + 32));
    bf16x8 v1hi = __builtin_bit_cast(bf16x8, *(const ushort8*)(vhi + kt + 32));
    uint2 mw = *(const uint2*)(mrow + (kt >> 5));

    f32x4 z = {0.f, 0.f, 0.f, 0.f};
    f32x4 st0 = __builtin_amdgcn_mfma_f32_16x16x32_bf16(k0, qf, z, 0, 0, 0);
    f32x4 st1 = __builtin_amdgcn_mfma_f32_16x16x32_bf16(k1, qf, z, 0, 0, 0);
    f32x4 st2 = __builtin_amdgcn_mfma_f32_16x16x32_bf16(k2, qf, z, 0, 0, 0);
    f32x4 st3 = __builtin_amdgcn_mfma_f32_16x16x32_bf16(k3, qf, z, 0, 0, 0);

    // ---- half A: keys [kt, kt+32)
    {
      float s[8];
      #pragma unroll
      for (int r = 0; r < 4; ++r) {
        s[r]     = ((mw.x >> (4 * g + r)) & 1u)      ? MNEG : st0[r];
        s[4 + r] = ((mw.x >> (16 + 4 * g + r)) & 1u) ? MNEG : st1[r];
      }
      float pmax = fmaxf(fmaxf(fmaxf(s[0], s[1]), s[2]),
                         fmaxf(fmaxf(s[3], s[4]), fmaxf(fmaxf(s[5], s[6]), s[7])));
      if (!__all(pmax <= M + 8.0f)) {
        float rmax = fmaxf(pmax, __shfl_xor(pmax, 16));
        rmax = fmaxf(rmax, __shfl_xor(rmax, 32));
        float Mn = fmaxf(M, rmax);
        float al = __builtin_amdgcn_exp2f(M - Mn);
        M = Mn; Lp *= al;
        #pragma unroll
        for (int r = 0; r < 4; ++r) {
          float ar = __shfl(al, 4 * g + r);
          olo[r] *= ar; ohi[r] *= ar;
        }
      }
      float p[8];
      #pragma unroll
      for (int j = 0; j < 8; ++j) p[j] = __builtin_amdgcn_exp2f(s[j] - M);
      Lp += ((p[0] + p[1]) + (p[2] + p[3])) + ((p[4] + p[5]) + (p[6] + p[7]));
      bf16x8 af;
      #pragma unroll
      for (int j = 0; j < 8; ++j) af[j] = (__bf16)p[j];
      olo = __builtin_amdgcn_mfma_f32_16x16x32_bf16(af, v0lo, olo, 0, 0, 0);
      ohi = __builtin_amdgcn_mfma_f32_16x16x32_bf16(af, v0hi, ohi, 0, 0, 0);
    }
    // ---- half B: keys [kt+32, kt+64)
    {
      float s[8];
      #pragma unroll
      for (int r = 0; r < 4; ++r) {
        s[r]     = ((mw.y >> (4 * g + r)) & 1u)      ? MNEG : st2[r];
        s[4 + r] = ((mw.y >> (16 + 4 * g + r)) & 1u) ? MNEG : st3[r];
      }
      float pmax = fmaxf(fmaxf(fmaxf(s[0], s[1]), s[2]),
                         fmaxf(fmaxf(s[3], s[4]), fmaxf(fmaxf(s[5], s[6]), s[7])));
      if (!__all(pmax <= M + 8.0f)) {
        float rmax = fmaxf(pmax, __shfl_xor(pmax, 16));
        rmax = fmaxf(rmax, __shfl_xor(rmax, 32));
        float Mn = fmaxf(M, rmax);
        float al = __builtin_amdgcn_exp2f(M - Mn);
        M = Mn; Lp *= al;
        #pragma unroll
        for (int r = 0; r < 4; ++r) {
          float ar = __shfl(al, 4 * g + r);
          olo[r] *= ar; ohi[r] *= ar;
        }
      }
      float p[8];
      #pragma unroll
      for (int j = 0; j < 8; ++j) p[j] = __builtin_amdgcn_exp2f(s[j] - M);
      Lp += ((p[0] + p[1]) + (p[2] + p[3])) + ((p[4] + p[5]) + (p[6] + p[7]));
      bf16x8 af;
      #pragma unroll
      for (int j = 0; j < 8; ++j) af[j] = (__bf16)p[j];
      olo = __builtin_amdgcn_mfma_f32_16x16x32_bf16(af, v1lo, olo, 0, 0, 0);
      ohi = __builtin_amdgcn_mfma_f32_16x16x32_bf16(af, v1hi, ohi, 0, 0, 0);
    }
  }

  // per-row L (sum over the 4 g-replicas), M already row-uniform
  Lp += __shfl_xor(Lp, 16);
  Lp += __shfl_xor(Lp, 32);

  if (lane < 16) { sM[w][lane] = M; sL[w][lane] = Lp; }
  #pragma unroll
  for (int r = 0; r < 4; ++r) {
    sO[w][r][lane]     = olo[r];
    sO[w][4 + r][lane] = ohi[r];
  }
  __syncthreads();

  if (w == 0) {
    float* ob = out + (size_t)h * Ss * Dd + (size_t)q0 * Dd;
    #pragma unroll
    for (int r = 0; r < 4; ++r) {
      int row = 4 * g + r;
      float M0 = sM[0][row], M1 = sM[1][row], M2 = sM[2][row], M3 = sM[3][row];
      float Mg = fmaxf(fmaxf(M0, M1), fmaxf(M2, M3));
      float e0 = __builtin_amdgcn_exp2f(M0 - Mg);
      float e1 = __builtin_amdgcn_exp2f(M1 - Mg);
      float e2 = __builtin_amdgcn_exp2f(M2 - Mg);
      float e3 = __builtin_amdgcn_exp2f(M3 - Mg);
      float den = sL[0][row] * e0 + sL[1][row] * e1 + sL[2][row] * e2 + sL[3][row] * e3;
      float nlo = sO[0][r][lane] * e0 + sO[1][r][lane] * e1 +
                  sO[2][r][lane] * e2 + sO[3][r][lane] * e3;
      float nhi = sO[0][4 + r][lane] * e0 + sO[1][4 + r][lane] * e1 +
                  sO[2][4 + r][lane] * e2 + sO[3][4 + r][lane] * e3;
      float inv = 1.0f / den;
      ob[row * Dd + li]      = nlo * inv;
      ob[row * Dd + li + 16] = nhi * inv;
    }
  }
}

extern "C" void kernel_launch(void* const* d_in, const int* in_sizes, int n_in,
                              void* d_out, int out_size, void* d_ws, size_t ws_size,
                              hipStream_t stream) {
  const float* query = (const float*)d_in[0];
  const float* key   = (const float*)d_in[1];
  const float* value = (const float*)d_in[2];
  const int*   mask  = (const int*)d_in[3];
  const float* Wq = (const float*)d_in[4];
  const float* bq = (const float*)d_in[5];
  const float* Wk = (const float*)d_in[6];
  const float* bk = (const float*)d_in[7];
  const float* Wv = (const float*)d_in[8];
  const float* bv = (const float*)d_in[9];
  const float* inv_scale = (const float*)d_in[10];

  unsigned short* Qb   = (unsigned short*)d_ws;
  unsigned short* Kbuf = Qb + (size_t)Hh * Ss * Dd;
  unsigned short* Vtb  = Kbuf + (size_t)Hh * Ss * Dd;
  unsigned int*   bits = (unsigned int*)(Vtb + (size_t)Hh * Dd * Ss);
  unsigned short* Wb   = (unsigned short*)(bits + (size_t)Ss * Ss / 32);
  float* out = (float*)d_out;

  dim3 blk(256);
  prep_kernel<<<512 + 48, blk, 0, stream>>>(mask, bits, Wq, Wk, Wv, Wb);
  proj_kernel<<<3072, blk, 0, stream>>>(query, key, value, Wb, bq, bk, bv,
                                        inv_scale, Qb, Kbuf, Vtb);
  attn_kernel<<<4096, blk, 0, stream>>>(Qb, Kbuf, Vtb, bits, out);
}